// Round 4
// baseline (76.302 us; speedup 1.0000x reference)
//
#include <hip/hip_runtime.h>

typedef __bf16 bf16;
typedef __attribute__((ext_vector_type(8))) __bf16 bf16x8;
typedef __attribute__((ext_vector_type(4))) __bf16 bf16x4;
typedef __attribute__((ext_vector_type(4))) float f32x4;

static constexpr int ROWS = 16384;   // BS*N_AGENTS

// ---------------- workspace layout (bf16 elements) ----------------
// Swizzled weights: element (n,k) of an [N,K] matrix lives at
//   ((n/16)*(K/32) + k/32)*512 + lane*8 + (k&7),  lane = (n&15) | (((k>>3)&3)<<4)
// so a wave's MFMA B-fragment (n16, k32) is one contiguous 1 KB block.
static constexpr size_t OFF_WFC1 = 0;        // [256,128]
static constexpr size_t OFF_WRX  = 32768;    // [256,256] Wih rows 0-255
static constexpr size_t OFF_WZX  = 98304;    // [256,256] Wih rows 256-511
static constexpr size_t OFF_WNI  = 163840;   // [256,256] Wih rows 512-767
static constexpr size_t OFF_WRH  = 229376;   // [256,256] Whh rows 0-255
static constexpr size_t OFF_WZH  = 294912;   // [256,256] Whh rows 256-511
static constexpr size_t OFF_WNH  = 360448;   // [256,256] Whh rows 512-767
static constexpr size_t OFF_WQ   = 425984;   // [64,256]
static constexpr size_t OFF_WKV  = 442368;   // [320,256]: kw n16 0-3, vw n16 4-19
static constexpr size_t OFF_F2AH = 524288;   // [256,256] f2aw cols 0-255
static constexpr size_t OFF_F2AM = 589824;   // [256,256] f2aw cols 256-511
static constexpr size_t OFF_WF2B = 655360;   // [16,256]
static constexpr size_t OFF_HNEW = 659456;   // [16384,256] h (bf16)
static constexpr size_t OFF_MSGK = 4853760;  // [16384,64]
static constexpr size_t OFF_MSGV = 5902336;  // [16384,256]

// ---------------- weight swizzle (f32 row-major -> bf16 fragment-major) ----------------
struct SwzSeg { const float* src; bf16* dst; int items; int k8s; int k32; int ld; };
struct SwzArgs { SwzSeg seg[13]; int count; };

__global__ __launch_bounds__(256) void swz_k(SwzArgs a) {
    const int tid = blockIdx.x * 256 + threadIdx.x;
    const int stride = gridDim.x * 256;
    for (int s = 0; s < a.count; ++s) {
        const float* __restrict__ src = a.seg[s].src;
        bf16* __restrict__ dst = a.seg[s].dst;
        const int items = a.seg[s].items, k8s = a.seg[s].k8s;
        const int k32c = a.seg[s].k32, ld = a.seg[s].ld;
        for (int i = tid; i < items; i += stride) {
            const int n = i >> k8s, kb = i & ((1 << k8s) - 1);
            const int k0 = kb << 3;
            const int lane = (n & 15) | ((kb & 3) << 4);
            const size_t off = ((size_t)((n >> 4) * k32c + (kb >> 2)) * 64 + lane) * 8;
            const float* p = src + (size_t)n * ld + k0;
            float4 f0 = *(const float4*)p;
            float4 f1 = *(const float4*)(p + 4);
            bf16x8 o = { (bf16)f0.x, (bf16)f0.y, (bf16)f0.z, (bf16)f0.w,
                         (bf16)f1.x, (bf16)f1.y, (bf16)f1.z, (bf16)f1.w };
            *(bf16x8*)(dst + off) = o;
        }
    }
}

// ---------------- MFMA helpers over swizzled B ----------------
template<int FM, int FN, int K32>
__device__ __forceinline__ void mm_swz(f32x4 (&acc)[FM][FN],
    const bf16* __restrict__ sA, int lda,
    const bf16* __restrict__ W /* pre-offset to wave's n16 base */, int lane)
{
    const int lr = lane & 15, lk = (lane >> 4) << 3;
    #pragma unroll
    for (int k32 = 0; k32 < K32; ++k32) {
        bf16x8 a[FM], b[FN];
        #pragma unroll
        for (int i = 0; i < FM; ++i)
            a[i] = *(const bf16x8*)&sA[(i * 16 + lr) * lda + k32 * 32 + lk];
        #pragma unroll
        for (int j = 0; j < FN; ++j)
            b[j] = *(const bf16x8*)(W + ((size_t)(j * K32 + k32) * 64 + lane) * 8);
        #pragma unroll
        for (int i = 0; i < FM; ++i)
            #pragma unroll
            for (int j = 0; j < FN; ++j)
                acc[i][j] = __builtin_amdgcn_mfma_f32_16x16x32_bf16(a[i], b[j], acc[i][j], 0, 0, 0);
    }
}

// three B matrices sharing one A stream (A loaded once per k32)
template<int K32>
__device__ __forceinline__ void mm3_swz(f32x4 (&a1)[2][4], f32x4 (&a2)[2][4], f32x4 (&a3)[2][4],
    const bf16* __restrict__ sA, int lda,
    const bf16* __restrict__ B1, const bf16* __restrict__ B2, const bf16* __restrict__ B3,
    int lane)
{
    const int lr = lane & 15, lk = (lane >> 4) << 3;
    #pragma unroll
    for (int k32 = 0; k32 < K32; ++k32) {
        bf16x8 a[2], b1[4], b2[4], b3[4];
        #pragma unroll
        for (int i = 0; i < 2; ++i)
            a[i] = *(const bf16x8*)&sA[(i * 16 + lr) * lda + k32 * 32 + lk];
        #pragma unroll
        for (int j = 0; j < 4; ++j) {
            const size_t bo = ((size_t)(j * K32 + k32) * 64 + lane) * 8;
            b1[j] = *(const bf16x8*)(B1 + bo);
            b2[j] = *(const bf16x8*)(B2 + bo);
            b3[j] = *(const bf16x8*)(B3 + bo);
        }
        #pragma unroll
        for (int i = 0; i < 2; ++i)
            #pragma unroll
            for (int j = 0; j < 4; ++j) {
                a1[i][j] = __builtin_amdgcn_mfma_f32_16x16x32_bf16(a[i], b1[j], a1[i][j], 0, 0, 0);
                a2[i][j] = __builtin_amdgcn_mfma_f32_16x16x32_bf16(a[i], b2[j], a2[i][j], 0, 0, 0);
                a3[i][j] = __builtin_amdgcn_mfma_f32_16x16x32_bf16(a[i], b3[j], a3[i][j], 0, 0, 0);
            }
    }
}

__device__ __forceinline__ float sigmf(float x) { return 1.f / (1.f + __expf(-x)); }
__device__ __forceinline__ float tanh_fast(float x) {
    x = fminf(fmaxf(x, -15.f), 15.f);
    float e2 = __expf(2.f * x);
    return (e2 - 1.f) / (e2 + 1.f);
}

// ---------------- GRU kernel: BM=64, 8 waves (2x4), unified tile mapping ----------------
// Every gate pass uses the same wave tile [32 rows, 64 cols], so r,z,i_n,h_n for one
// output element stay in one thread's registers. Phase A: fc1 + H-side gates (no sX dep);
// phase B: X-side gates; then full epilogue.
__global__ __launch_bounds__(512, 2)
void gru_k(const float* __restrict__ in_f, const float* __restrict__ hid_f,
           const bf16* __restrict__ Wfc1, const float* __restrict__ fc1_b,
           const bf16* __restrict__ WrX, const bf16* __restrict__ WrH,
           const bf16* __restrict__ WzX, const bf16* __restrict__ WzH,
           const bf16* __restrict__ Wni, const bf16* __restrict__ Wnh,
           const float* __restrict__ b_ih, const float* __restrict__ b_hh,
           float* __restrict__ h_out, bf16* __restrict__ hnew)
{
    __shared__ bf16 sIn[64 * 136];
    __shared__ bf16 sX[64 * 264];
    __shared__ bf16 sH[64 * 264];
    const int tid = threadIdx.x;
    const int wave = tid >> 6, lane = tid & 63;
    const int wm = wave >> 2, wn = wave & 3;     // 2 row-waves x 4 col-waves
    const int m0 = blockIdx.x * 64;
    const int lr = lane & 15, l4 = (lane >> 4) << 2;

    // stage in [64,128], hidden [64,256] (f32 -> bf16)
    for (int c = tid; c < 2048; c += 512) {
        int r = c >> 5, cg = (c & 31) << 2;
        float4 f = *(const float4*)(in_f + (size_t)(m0 + r) * 128 + cg);
        bf16x4 o = { (bf16)f.x, (bf16)f.y, (bf16)f.z, (bf16)f.w };
        *(bf16x4*)&sIn[r * 136 + cg] = o;
    }
    for (int c = tid; c < 4096; c += 512) {
        int r = c >> 6, cg = (c & 63) << 2;
        float4 f = *(const float4*)(hid_f + (size_t)(m0 + r) * 256 + cg);
        bf16x4 o = { (bf16)f.x, (bf16)f.y, (bf16)f.z, (bf16)f.w };
        *(bf16x4*)&sH[r * 264 + cg] = o;
    }
    __syncthreads();

    const bf16* sHa = sH + wm * 32 * 264;
    const bf16* sXa = sX + wm * 32 * 264;
    const size_t nb8 = (size_t)(wn * 4) * 8 * 512;   // n16 base, K=256 matrices

    // phase A: fc1 acc + H-side gates (ra, za, nh)
    f32x4 ra[2][4] = {}, za[2][4] = {}, nh[2][4] = {};
    {
        f32x4 fa[2][4] = {};
        mm_swz<2, 4, 4>(fa, sIn + wm * 32 * 136, 136, Wfc1 + (size_t)(wn * 4) * 4 * 512, lane);
        mm3_swz<8>(ra, za, nh, sHa, 264, WrH + nb8, WzH + nb8, Wnh + nb8, lane);
        // X = relu(fc1) -> sX
        #pragma unroll
        for (int i = 0; i < 2; ++i)
            #pragma unroll
            for (int j = 0; j < 4; ++j) {
                const int col = wn * 64 + j * 16 + lr;
                const float bv = fc1_b[col];
                #pragma unroll
                for (int rr = 0; rr < 4; ++rr) {
                    const int row = wm * 32 + i * 16 + l4 + rr;
                    sX[row * 264 + col] = (bf16)fmaxf(fa[i][j][rr] + bv, 0.f);
                }
            }
    }
    __syncthreads();

    // phase B: X-side gates (ra, za, ni)
    f32x4 ni[2][4] = {};
    mm3_swz<8>(ra, za, ni, sXa, 264, WrX + nb8, WzX + nb8, Wni + nb8, lane);

    // GRU epilogue (all register-local)
    #pragma unroll
    for (int i = 0; i < 2; ++i)
        #pragma unroll
        for (int j = 0; j < 4; ++j) {
            const int col = wn * 64 + j * 16 + lr;
            const float br = b_ih[col] + b_hh[col];
            const float bz = b_ih[256 + col] + b_hh[256 + col];
            const float bi = b_ih[512 + col], bh = b_hh[512 + col];
            #pragma unroll
            for (int rr = 0; rr < 4; ++rr) {
                const int row = wm * 32 + i * 16 + l4 + rr;
                const size_t grow = m0 + row;
                float rv = sigmf(ra[i][j][rr] + br);
                float zv = sigmf(za[i][j][rr] + bz);
                float nn = tanh_fast((ni[i][j][rr] + bi) + rv * (nh[i][j][rr] + bh));
                float hd = (float)sH[row * 264 + col];
                float h = (1.f - zv) * nn + zv * hd;
                h_out[grow * 256 + col] = h;
                hnew[grow * 256 + col] = (bf16)h;
            }
        }
}

// ---------------- msg K/V projection: BM=64, N=320 ----------------
__global__ __launch_bounds__(512)
void msgkv_k(const float* __restrict__ msg_f, const bf16* __restrict__ Wkv,
             bf16* __restrict__ msgk, bf16* __restrict__ msgv)
{
    __shared__ bf16 sA[64 * 264];
    const int tid = threadIdx.x;
    const int wave = tid >> 6, lane = tid & 63;
    const int wm = wave >> 2, wn = wave & 3;
    const int m0 = blockIdx.x * 64;
    const int lr = lane & 15, l4 = (lane >> 4) << 2;

    for (int c = tid; c < 4096; c += 512) {
        int r = c >> 6, cg = (c & 63) << 2;
        float4 f = *(const float4*)(msg_f + (size_t)(m0 + r) * 256 + cg);
        bf16x4 o = { (bf16)f.x, (bf16)f.y, (bf16)f.z, (bf16)f.w };
        *(bf16x4*)&sA[r * 264 + cg] = o;
    }
    __syncthreads();

    f32x4 acc[2][5] = {};
    mm_swz<2, 5, 8>(acc, sA + wm * 32 * 264, 264, Wkv + (size_t)(wn * 5) * 8 * 512, lane);

    #pragma unroll
    for (int i = 0; i < 2; ++i)
        #pragma unroll
        for (int j = 0; j < 5; ++j) {
            const int col = wn * 80 + j * 16 + lr;
            #pragma unroll
            for (int rr = 0; rr < 4; ++rr) {
                const size_t row = m0 + wm * 32 + i * 16 + l4 + rr;
                if (col < 64) msgk[row * 64 + col] = (bf16)acc[i][j][rr];
                else          msgv[row * 256 + col - 64] = (bf16)acc[i][j][rr];
            }
        }
}

// ---------------- q-proj + attention + fc2a + fc2b, one block per batch ----------------
__global__ __launch_bounds__(512)
void attnfc2_k(const bf16* __restrict__ hnew, const bf16* __restrict__ msgk,
               const bf16* __restrict__ msgv, const int* __restrict__ topk,
               const bf16* __restrict__ Wq, const float* __restrict__ q_b,
               const float* __restrict__ v_bias,
               const bf16* __restrict__ f2aH, const bf16* __restrict__ f2aM,
               const float* __restrict__ f2a_b,
               const bf16* __restrict__ Wf2b, const float* __restrict__ f2b_b,
               float* __restrict__ magg_out, float* __restrict__ q_out)
{
    __shared__ bf16 sH[64 * 264];
    __shared__ bf16 sV[64 * 264];   // V, later reused as y (fc2a output)
    __shared__ bf16 sM[64 * 264];
    __shared__ bf16 sQ[64 * 72];
    __shared__ bf16 sK[64 * 72];
    __shared__ int  sIdx[512];
    const int tid = threadIdx.x;
    const int wave = tid >> 6, lane = tid & 63;
    const int wm = wave >> 2, wn = wave & 3;
    const int b64 = blockIdx.x * 64;
    const int lr = lane & 15, l4 = (lane >> 4) << 2;

    // stage h (bf16 direct), K, V, topk
    for (int c = tid; c < 2048; c += 512) {
        int r = c >> 5, cg = (c & 31) << 3;
        *(bf16x8*)&sH[r * 264 + cg] = *(const bf16x8*)(hnew + (size_t)(b64 + r) * 256 + cg);
        *(bf16x8*)&sV[r * 264 + cg] = *(const bf16x8*)(msgv + (size_t)(b64 + r) * 256 + cg);
    }
    for (int c = tid; c < 512; c += 512) {
        int r = c >> 3, cg = (c & 7) << 3;
        *(bf16x8*)&sK[r * 72 + cg] = *(const bf16x8*)(msgk + (size_t)(b64 + r) * 64 + cg);
        sIdx[c] = topk[(size_t)b64 * 8 + c];
    }
    __syncthreads();

    // q = h @ qw^T + q_b -> sQ  (wave tile [32,16])
    {
        f32x4 qa[2][1] = {};
        mm_swz<2, 1, 8>(qa, sH + wm * 32 * 264, 264, Wq + (size_t)wn * 8 * 512, lane);
        #pragma unroll
        for (int i = 0; i < 2; ++i) {
            const int col = wn * 16 + lr;
            const float bv = q_b[col];
            #pragma unroll
            for (int rr = 0; rr < 4; ++rr) {
                const int row = wm * 32 + i * 16 + l4 + rr;
                sQ[row * 72 + col] = (bf16)(qa[i][0][rr] + bv);
            }
        }
    }
    __syncthreads();

    // attention: wave handles units wave*8 .. wave*8+7
    const int kk = lane >> 3, dg = lane & 7;
    #pragma unroll
    for (int uu = 0; uu < 8; ++uu) {
        const int u = wave * 8 + uu;
        const int rowk = sIdx[u * 8 + kk];
        bf16x8 q8 = *(const bf16x8*)&sQ[u * 72 + dg * 8];
        bf16x8 k8 = *(const bf16x8*)&sK[rowk * 72 + dg * 8];
        float s = 0.f;
        #pragma unroll
        for (int t = 0; t < 8; ++t) s += (float)q8[t] * (float)k8[t];
        s += __shfl_xor(s, 1); s += __shfl_xor(s, 2); s += __shfl_xor(s, 4);
        float logit = s * 0.125f;
        float mx = logit;
        mx = fmaxf(mx, __shfl_xor(mx, 8));
        mx = fmaxf(mx, __shfl_xor(mx, 16));
        mx = fmaxf(mx, __shfl_xor(mx, 32));
        float e = __expf(logit - mx);
        float den = e;
        den += __shfl_xor(den, 8); den += __shfl_xor(den, 16); den += __shfl_xor(den, 32);
        const float wv = e / den;
        float a0 = 0.f, a1 = 0.f, a2 = 0.f, a3 = 0.f;
        #pragma unroll
        for (int k = 0; k < 8; ++k) {
            float wk = __shfl(wv, k * 8);
            int   rk = __shfl(rowk, k * 8);
            bf16x4 v = *(const bf16x4*)&sV[rk * 264 + lane * 4];
            a0 += wk * (float)v[0]; a1 += wk * (float)v[1];
            a2 += wk * (float)v[2]; a3 += wk * (float)v[3];
        }
        float4 vb = *(const float4*)(v_bias + lane * 4);
        a0 += vb.x; a1 += vb.y; a2 += vb.z; a3 += vb.w;
        float4 res = { a0, a1, a2, a3 };
        *(float4*)(magg_out + (size_t)(b64 + u) * 256 + lane * 4) = res;
        bf16x4 rb = { (bf16)a0, (bf16)a1, (bf16)a2, (bf16)a3 };
        *(bf16x4*)&sM[u * 264 + lane * 4] = rb;
    }
    __syncthreads();

    // fc2a: y = relu([h|m] @ f2aw^T + b) -> sV (reused)
    {
        f32x4 acc[2][4] = {};
        mm_swz<2, 4, 8>(acc, sH + wm * 32 * 264, 264, f2aH + (size_t)(wn * 4) * 8 * 512, lane);
        mm_swz<2, 4, 8>(acc, sM + wm * 32 * 264, 264, f2aM + (size_t)(wn * 4) * 8 * 512, lane);
        __syncthreads();   // all sV (V) reads complete before overwrite
        #pragma unroll
        for (int i = 0; i < 2; ++i)
            #pragma unroll
            for (int j = 0; j < 4; ++j) {
                const int col = wn * 64 + j * 16 + lr;
                const float bv = f2a_b[col];
                #pragma unroll
                for (int rr = 0; rr < 4; ++rr) {
                    const int row = wm * 32 + i * 16 + l4 + rr;
                    sV[row * 264 + col] = (bf16)fmaxf(acc[i][j][rr] + bv, 0.f);
                }
            }
    }
    __syncthreads();

    // fc2b: q_out = y @ f2bw^T + b  (waves 0-3, [16,16] tiles)
    if (wave < 4) {
        f32x4 acc[1][1] = {};
        mm_swz<1, 1, 8>(acc, sV + wave * 16 * 264, 264, Wf2b, lane);
        const float bv = f2b_b[lr];
        #pragma unroll
        for (int rr = 0; rr < 4; ++rr) {
            const size_t row = b64 + wave * 16 + l4 + rr;
            q_out[row * 16 + lr] = acc[0][0][rr] + bv;
        }
    }
}

// ---------------- launch ----------------
extern "C" void kernel_launch(void* const* d_in, const int* in_sizes, int n_in,
                              void* d_out, int out_size, void* d_ws, size_t ws_size,
                              hipStream_t stream)
{
    const float* in_f   = (const float*)d_in[0];
    const float* hid_f  = (const float*)d_in[1];
    const float* msg_f  = (const float*)d_in[2];
    const int*   topk   = (const int*)d_in[3];
    const float* fc1w_f = (const float*)d_in[4];
    const float* fc1_b  = (const float*)d_in[5];
    const float* wih_f  = (const float*)d_in[6];
    const float* b_ih   = (const float*)d_in[7];
    const float* whh_f  = (const float*)d_in[8];
    const float* b_hh   = (const float*)d_in[9];
    const float* qw_f   = (const float*)d_in[10];
    const float* q_b    = (const float*)d_in[11];
    const float* kw_f   = (const float*)d_in[12];
    // d_in[13] = k_b: softmax-invariant, dropped.
    const float* vw_f   = (const float*)d_in[14];
    const float* v_b    = (const float*)d_in[15];
    const float* f2aw_f = (const float*)d_in[16];
    const float* f2a_b  = (const float*)d_in[17];
    const float* f2bw_f = (const float*)d_in[18];
    const float* f2b_b  = (const float*)d_in[19];

    bf16* ws = (bf16*)d_ws;
    bf16* Wfc1 = ws + OFF_WFC1;
    bf16* WrX  = ws + OFF_WRX;
    bf16* WzX  = ws + OFF_WZX;
    bf16* Wni  = ws + OFF_WNI;
    bf16* WrH  = ws + OFF_WRH;
    bf16* WzH  = ws + OFF_WZH;
    bf16* Wnh  = ws + OFF_WNH;
    bf16* Wq   = ws + OFF_WQ;
    bf16* Wkv  = ws + OFF_WKV;
    bf16* f2aH = ws + OFF_F2AH;
    bf16* f2aM = ws + OFF_F2AM;
    bf16* Wf2b = ws + OFF_WF2B;
    bf16* hnew = ws + OFF_HNEW;
    bf16* msgk = ws + OFF_MSGK;
    bf16* msgv = ws + OFF_MSGV;

    float* q_out    = (float*)d_out;                 // [16384,16]
    float* h_out    = q_out + (size_t)ROWS * 16;     // [16384,256]
    float* magg_out = h_out + (size_t)ROWS * 256;    // [16384,256]

    // 1) swizzle weights to fragment-major bf16
    SwzArgs sa{};
    int s = 0;
    auto add = [&](const float* src, bf16* dst, int N, int K, int ld) {
        sa.seg[s].src = src; sa.seg[s].dst = dst;
        sa.seg[s].items = N * (K >> 3);
        sa.seg[s].k8s = (K == 128) ? 4 : 5;
        sa.seg[s].k32 = K >> 5;
        sa.seg[s].ld = ld; ++s;
    };
    add(fc1w_f,          Wfc1, 256, 128, 128);
    add(wih_f,           WrX,  256, 256, 256);
    add(wih_f +  65536,  WzX,  256, 256, 256);
    add(wih_f + 131072,  Wni,  256, 256, 256);
    add(whh_f,           WrH,  256, 256, 256);
    add(whh_f +  65536,  WzH,  256, 256, 256);
    add(whh_f + 131072,  Wnh,  256, 256, 256);
    add(qw_f,            Wq,    64, 256, 256);
    add(kw_f,            Wkv,   64, 256, 256);
    add(vw_f,            Wkv + 16384, 256, 256, 256);
    add(f2aw_f,          f2aH, 256, 256, 512);
    add(f2aw_f + 256,    f2aM, 256, 256, 512);
    add(f2bw_f,          Wf2b,  16, 256, 256);
    sa.count = s;
    swz_k<<<256, 256, 0, stream>>>(sa);

    // 2) fused fc1 + GRU (BM=64, 256 blocks = 1/CU)
    gru_k<<<256, 512, 0, stream>>>(in_f, hid_f, Wfc1, fc1_b,
                                   WrX, WrH, WzX, WzH, Wni, Wnh,
                                   b_ih, b_hh, h_out, hnew);

    // 3) msg K/V projections
    msgkv_k<<<256, 512, 0, stream>>>(msg_f, Wkv, msgk, msgv);

    // 4) q-proj + attention + fc2a + fc2b
    attnfc2_k<<<256, 512, 0, stream>>>(hnew, msgk, msgv, topk,
                                       Wq, q_b, v_b, f2aH, f2aM, f2a_b,
                                       Wf2b, f2b_b, magg_out, q_out);
}

// Round 5
// 72.854 us; speedup vs baseline: 1.0473x; 1.0473x over previous
//
#include <hip/hip_runtime.h>

typedef __bf16 bf16;
typedef __attribute__((ext_vector_type(8))) __bf16 bf16x8;
typedef __attribute__((ext_vector_type(4))) __bf16 bf16x4;
typedef __attribute__((ext_vector_type(4))) float f32x4;

static constexpr int ROWS = 16384;   // BS*N_AGENTS

// ---------------- workspace layout (bf16 elements) ----------------
// Fragment-major swizzle: element (n,k) of an [N,K] matrix lives at
//   ((n/16)*(K/32) + k/32)*512 + lane*8 + (k&7),  lane = (n&15) | (((k>>3)&3)<<4)
// so a wave's MFMA fragment (n16, k32) is one contiguous 1 KB block. Same
// formula serves A-side fragments (n -> m).
static constexpr size_t OFF_WFC1 = 0;        // [256,128]
static constexpr size_t OFF_WRX  = 32768;    // [256,256] Wih rows 0-255
static constexpr size_t OFF_WZX  = 98304;    // [256,256] Wih rows 256-511
static constexpr size_t OFF_WNI  = 163840;   // [256,256] Wih rows 512-767
static constexpr size_t OFF_WRH  = 229376;   // [256,256] Whh rows 0-255
static constexpr size_t OFF_WZH  = 294912;   // [256,256] Whh rows 256-511
static constexpr size_t OFF_WNH  = 360448;   // [256,256] Whh rows 512-767
static constexpr size_t OFF_WQ   = 425984;   // [64,256]
static constexpr size_t OFF_WKV  = 442368;   // [320,256]: kw n16 0-3, vw n16 4-19
static constexpr size_t OFF_F2AH = 524288;   // [256,256] f2aw cols 0-255
static constexpr size_t OFF_F2AM = 589824;   // [256,256] f2aw cols 256-511
static constexpr size_t OFF_WF2B = 655360;   // [16,256]
static constexpr size_t OFF_INSW = 659456;   // [16384,128] 'in' activations, frag-major

// ---------------- swizzle (f32 row-major -> bf16 fragment-major) ----------------
struct SwzSeg { const float* src; bf16* dst; int items; int k8s; int k32; int ld; };
struct SwzArgs { SwzSeg seg[14]; int count; };

__global__ __launch_bounds__(256) void swz_k(SwzArgs a) {
    const int tid = blockIdx.x * 256 + threadIdx.x;
    const int stride = gridDim.x * 256;
    for (int s = 0; s < a.count; ++s) {
        const float* __restrict__ src = a.seg[s].src;
        bf16* __restrict__ dst = a.seg[s].dst;
        const int items = a.seg[s].items, k8s = a.seg[s].k8s;
        const int k32c = a.seg[s].k32, ld = a.seg[s].ld;
        for (int i = tid; i < items; i += stride) {
            const int n = i >> k8s, kb = i & ((1 << k8s) - 1);
            const int k0 = kb << 3;
            const int lane = (n & 15) | ((kb & 3) << 4);
            const size_t off = ((size_t)((n >> 4) * k32c + (kb >> 2)) * 64 + lane) * 8;
            const float* p = src + (size_t)n * ld + k0;
            float4 f0 = *(const float4*)p;
            float4 f1 = *(const float4*)(p + 4);
            bf16x8 o = { (bf16)f0.x, (bf16)f0.y, (bf16)f0.z, (bf16)f0.w,
                         (bf16)f1.x, (bf16)f1.y, (bf16)f1.z, (bf16)f1.w };
            *(bf16x8*)(dst + off) = o;
        }
    }
}

// ---------------- MFMA helpers ----------------
// A from row-major LDS, B from fragment-major global (pre-offset to wave n16 base)
template<int FM, int FN, int K32>
__device__ __forceinline__ void mm_swz(f32x4 (&acc)[FM][FN],
    const bf16* __restrict__ sA, int lda,
    const bf16* __restrict__ W, int lane)
{
    const int lr = lane & 15, lk = (lane >> 4) << 3;
    #pragma unroll
    for (int k32 = 0; k32 < K32; ++k32) {
        bf16x8 a[FM], b[FN];
        #pragma unroll
        for (int i = 0; i < FM; ++i)
            a[i] = *(const bf16x8*)&sA[(i * 16 + lr) * lda + k32 * 32 + lk];
        #pragma unroll
        for (int j = 0; j < FN; ++j)
            b[j] = *(const bf16x8*)(W + ((size_t)(j * K32 + k32) * 64 + lane) * 8);
        #pragma unroll
        for (int i = 0; i < FM; ++i)
            #pragma unroll
            for (int j = 0; j < FN; ++j)
                acc[i][j] = __builtin_amdgcn_mfma_f32_16x16x32_bf16(a[i], b[j], acc[i][j], 0, 0, 0);
    }
}

// A and B both fragment-major global (pre-offset)
template<int FM, int FN, int K32>
__device__ __forceinline__ void mm_gg(f32x4 (&acc)[FM][FN],
    const bf16* __restrict__ A, const bf16* __restrict__ W, int lane)
{
    #pragma unroll
    for (int k32 = 0; k32 < K32; ++k32) {
        bf16x8 a[FM], b[FN];
        #pragma unroll
        for (int i = 0; i < FM; ++i)
            a[i] = *(const bf16x8*)(A + ((size_t)(i * K32 + k32) * 64 + lane) * 8);
        #pragma unroll
        for (int j = 0; j < FN; ++j)
            b[j] = *(const bf16x8*)(W + ((size_t)(j * K32 + k32) * 64 + lane) * 8);
        #pragma unroll
        for (int i = 0; i < FM; ++i)
            #pragma unroll
            for (int j = 0; j < FN; ++j)
                acc[i][j] = __builtin_amdgcn_mfma_f32_16x16x32_bf16(a[i], b[j], acc[i][j], 0, 0, 0);
    }
}

__device__ __forceinline__ float sigmf(float x) { return 1.f / (1.f + __expf(-x)); }
__device__ __forceinline__ float tanh_fast(float x) {
    x = fminf(fmaxf(x, -15.f), 15.f);
    float e2 = __expf(2.f * x);
    return (e2 - 1.f) / (e2 + 1.f);
}

// ---------------- megakernel: one block per batch (64 agents), 8 waves ----------------
__global__ __launch_bounds__(512, 2)
void mega_k(const bf16* __restrict__ insw, const float* __restrict__ hid_f,
            const float* __restrict__ msg_f, const int* __restrict__ topk,
            const bf16* __restrict__ Wfc1, const float* __restrict__ fc1_b,
            const bf16* __restrict__ WrX, const bf16* __restrict__ WrH,
            const bf16* __restrict__ WzX, const bf16* __restrict__ WzH,
            const bf16* __restrict__ Wni, const bf16* __restrict__ Wnh,
            const float* __restrict__ b_ih, const float* __restrict__ b_hh,
            const bf16* __restrict__ Wq, const float* __restrict__ q_b,
            const bf16* __restrict__ Wkv, const float* __restrict__ v_bias,
            const bf16* __restrict__ f2aH, const bf16* __restrict__ f2aM,
            const float* __restrict__ f2a_b,
            const bf16* __restrict__ Wf2b, const float* __restrict__ f2b_b,
            float* __restrict__ h_out, float* __restrict__ magg_out,
            float* __restrict__ q_out)
{
    __shared__ bf16 sH[64 * 264];   // hidden (old), updated in place to h
    __shared__ bf16 sB[64 * 264];   // X (fc1 out), then V (msg@v_w^T)
    __shared__ bf16 sG[64 * 264];   // msg, then Y (fc2a out)
    __shared__ bf16 sM[64 * 264];   // m_agg
    __shared__ bf16 sQ[64 * 72];
    __shared__ bf16 sK[64 * 72];
    __shared__ int  sIdx[512];
    const int tid = threadIdx.x;
    const int wave = tid >> 6, lane = tid & 63;
    const int wm2 = wave >> 2, wn4 = wave & 3;    // 2x4 arrangement (kv/q phases)
    const int b64 = blockIdx.x * 64;
    const int lr = lane & 15, l4 = (lane >> 4) << 2;
    const int stg_r = tid >> 6, stg_c = (tid & 63) << 2;

    // --- early: issue msg loads into registers (latency hides under staging+fc1)
    float4 mr[8];
    #pragma unroll
    for (int u = 0; u < 8; ++u)
        mr[u] = *(const float4*)(msg_f + (size_t)(b64 + stg_r + u * 8) * 256 + stg_c);

    // --- stage hidden [64,256] f32 -> bf16
    #pragma unroll
    for (int u = 0; u < 8; ++u) {
        float4 f = *(const float4*)(hid_f + (size_t)(b64 + stg_r + u * 8) * 256 + stg_c);
        bf16x4 o = { (bf16)f.x, (bf16)f.y, (bf16)f.z, (bf16)f.w };
        *(bf16x4*)&sH[(stg_r + u * 8) * 264 + stg_c] = o;
    }
    sIdx[tid] = topk[(size_t)blockIdx.x * 512 + tid];
    __syncthreads();

    // --- fc1: X = relu(in @ fc1w^T + b) -> sB.  A frags direct from global.
    {
        f32x4 fa[4][2] = {};
        mm_gg<4, 2, 4>(fa, insw + (size_t)(b64 >> 4) * 4 * 512,
                       Wfc1 + (size_t)(wave * 2) * 4 * 512, lane);
        #pragma unroll
        for (int i = 0; i < 4; ++i)
            #pragma unroll
            for (int j = 0; j < 2; ++j) {
                const int col = wave * 32 + j * 16 + lr;
                const float bv = fc1_b[col];
                #pragma unroll
                for (int rr = 0; rr < 4; ++rr)
                    sB[(i * 16 + l4 + rr) * 264 + col] = (bf16)fmaxf(fa[i][j][rr] + bv, 0.f);
            }
    }
    // --- msg regs -> sG (bf16); not read until kv-proj (after 2 more syncs)
    #pragma unroll
    for (int u = 0; u < 8; ++u) {
        bf16x4 o = { (bf16)mr[u].x, (bf16)mr[u].y, (bf16)mr[u].z, (bf16)mr[u].w };
        *(bf16x4*)&sG[(stg_r + u * 8) * 264 + stg_c] = o;
    }
    __syncthreads();

    // --- GRU gates, spill-free order r -> n -> z. Wave tile [64 rows, 32 cols].
    const size_t nb = (size_t)(wave * 2) * 8 * 512;
    f32x4 rg[4][2] = {};
    mm_swz<4, 2, 8>(rg, sB, 264, WrX + nb, lane);
    mm_swz<4, 2, 8>(rg, sH, 264, WrH + nb, lane);
    #pragma unroll
    for (int i = 0; i < 4; ++i)
        #pragma unroll
        for (int j = 0; j < 2; ++j) {
            const int col = wave * 32 + j * 16 + lr;
            const float br = b_ih[col] + b_hh[col];
            #pragma unroll
            for (int rr = 0; rr < 4; ++rr) rg[i][j][rr] = sigmf(rg[i][j][rr] + br);
        }

    f32x4 ng[4][2] = {}, hg[4][2] = {};
    mm_swz<4, 2, 8>(ng, sB, 264, Wni + nb, lane);
    mm_swz<4, 2, 8>(hg, sH, 264, Wnh + nb, lane);
    #pragma unroll
    for (int i = 0; i < 4; ++i)
        #pragma unroll
        for (int j = 0; j < 2; ++j) {
            const int col = wave * 32 + j * 16 + lr;
            const float bi = b_ih[512 + col], bh = b_hh[512 + col];
            #pragma unroll
            for (int rr = 0; rr < 4; ++rr)
                ng[i][j][rr] = tanh_fast((ng[i][j][rr] + bi) + rg[i][j][rr] * (hg[i][j][rr] + bh));
        }

    f32x4 zg[4][2] = {};
    mm_swz<4, 2, 8>(zg, sB, 264, WzX + nb, lane);
    mm_swz<4, 2, 8>(zg, sH, 264, WzH + nb, lane);
    __syncthreads();   // all sB/sH MFMA reads complete

    // --- epilogue: h = (1-z)*n + z*h_old ; write h_out, update sH in place
    #pragma unroll
    for (int i = 0; i < 4; ++i)
        #pragma unroll
        for (int j = 0; j < 2; ++j) {
            const int col = wave * 32 + j * 16 + lr;
            const float bz = b_ih[256 + col] + b_hh[256 + col];
            #pragma unroll
            for (int rr = 0; rr < 4; ++rr) {
                const int row = i * 16 + l4 + rr;
                const float zv = sigmf(zg[i][j][rr] + bz);
                const float hd = (float)sH[row * 264 + col];
                const float h = (1.f - zv) * ng[i][j][rr] + zv * hd;
                h_out[(size_t)(b64 + row) * 256 + col] = h;
                sH[row * 264 + col] = (bf16)h;
            }
        }
    __syncthreads();

    // --- kv-proj: [K|V] = msg @ Wkv^T  (2x4 waves, tile [32,80]) -> sK, sB(V)
    {
        f32x4 a[2][5] = {};
        mm_swz<2, 5, 8>(a, sG + wm2 * 32 * 264, 264, Wkv + (size_t)(wn4 * 5) * 8 * 512, lane);
        #pragma unroll
        for (int i = 0; i < 2; ++i)
            #pragma unroll
            for (int j = 0; j < 5; ++j) {
                const int col = wn4 * 80 + j * 16 + lr;
                #pragma unroll
                for (int rr = 0; rr < 4; ++rr) {
                    const int row = wm2 * 32 + i * 16 + l4 + rr;
                    if (col < 64) sK[row * 72 + col] = (bf16)a[i][j][rr];
                    else          sB[row * 264 + col - 64] = (bf16)a[i][j][rr];
                }
            }
    }
    // --- q-proj: q = h @ qw^T + q_b  (2x4 waves, tile [32,16]) -> sQ
    {
        f32x4 qa[2][1] = {};
        mm_swz<2, 1, 8>(qa, sH + wm2 * 32 * 264, 264, Wq + (size_t)wn4 * 8 * 512, lane);
        #pragma unroll
        for (int i = 0; i < 2; ++i) {
            const int col = wn4 * 16 + lr;
            const float bv = q_b[col];
            #pragma unroll
            for (int rr = 0; rr < 4; ++rr)
                sQ[(wm2 * 32 + i * 16 + l4 + rr) * 72 + col] = (bf16)(qa[i][0][rr] + bv);
        }
    }
    __syncthreads();

    // --- attention: wave handles agents wave*8 .. wave*8+7
    const int kk = lane >> 3, dg = lane & 7;
    #pragma unroll
    for (int uu = 0; uu < 8; ++uu) {
        const int u = wave * 8 + uu;
        const int rowk = sIdx[u * 8 + kk];
        bf16x8 q8 = *(const bf16x8*)&sQ[u * 72 + dg * 8];
        bf16x8 k8 = *(const bf16x8*)&sK[rowk * 72 + dg * 8];
        float s = 0.f;
        #pragma unroll
        for (int t = 0; t < 8; ++t) s += (float)q8[t] * (float)k8[t];
        s += __shfl_xor(s, 1); s += __shfl_xor(s, 2); s += __shfl_xor(s, 4);
        float logit = s * 0.125f;
        float mx = logit;
        mx = fmaxf(mx, __shfl_xor(mx, 8));
        mx = fmaxf(mx, __shfl_xor(mx, 16));
        mx = fmaxf(mx, __shfl_xor(mx, 32));
        float e = __expf(logit - mx);
        float den = e;
        den += __shfl_xor(den, 8); den += __shfl_xor(den, 16); den += __shfl_xor(den, 32);
        const float wv = e / den;
        float a0 = 0.f, a1 = 0.f, a2 = 0.f, a3 = 0.f;
        #pragma unroll
        for (int k = 0; k < 8; ++k) {
            float wk = __shfl(wv, k * 8);
            int   rk = __shfl(rowk, k * 8);
            bf16x4 v = *(const bf16x4*)&sB[rk * 264 + lane * 4];
            a0 += wk * (float)v[0]; a1 += wk * (float)v[1];
            a2 += wk * (float)v[2]; a3 += wk * (float)v[3];
        }
        float4 vb = *(const float4*)(v_bias + lane * 4);
        a0 += vb.x; a1 += vb.y; a2 += vb.z; a3 += vb.w;
        float4 res = { a0, a1, a2, a3 };
        *(float4*)(magg_out + (size_t)(b64 + u) * 256 + lane * 4) = res;
        bf16x4 rb = { (bf16)a0, (bf16)a1, (bf16)a2, (bf16)a3 };
        *(bf16x4*)&sM[u * 264 + lane * 4] = rb;
    }
    __syncthreads();

    // --- fc2a: y = relu([h|m] @ f2aw^T + b) -> sG (reused as Y)
    {
        f32x4 acc[4][2] = {};
        mm_swz<4, 2, 8>(acc, sH, 264, f2aH + nb, lane);
        mm_swz<4, 2, 8>(acc, sM, 264, f2aM + nb, lane);
        #pragma unroll
        for (int i = 0; i < 4; ++i)
            #pragma unroll
            for (int j = 0; j < 2; ++j) {
                const int col = wave * 32 + j * 16 + lr;
                const float bv = f2a_b[col];
                #pragma unroll
                for (int rr = 0; rr < 4; ++rr)
                    sG[(i * 16 + l4 + rr) * 264 + col] = (bf16)fmaxf(acc[i][j][rr] + bv, 0.f);
            }
    }
    __syncthreads();

    // --- fc2b: q_out = y @ f2bw^T + b  (waves 0-3, [16,16] tiles)
    if (wave < 4) {
        f32x4 acc[1][1] = {};
        mm_swz<1, 1, 8>(acc, sG + wave * 16 * 264, 264, Wf2b, lane);
        const float bv = f2b_b[lr];
        #pragma unroll
        for (int rr = 0; rr < 4; ++rr)
            q_out[(size_t)(b64 + wave * 16 + l4 + rr) * 16 + lr] = acc[0][0][rr] + bv;
    }
}

// ---------------- launch ----------------
extern "C" void kernel_launch(void* const* d_in, const int* in_sizes, int n_in,
                              void* d_out, int out_size, void* d_ws, size_t ws_size,
                              hipStream_t stream)
{
    const float* in_f   = (const float*)d_in[0];
    const float* hid_f  = (const float*)d_in[1];
    const float* msg_f  = (const float*)d_in[2];
    const int*   topk   = (const int*)d_in[3];
    const float* fc1w_f = (const float*)d_in[4];
    const float* fc1_b  = (const float*)d_in[5];
    const float* wih_f  = (const float*)d_in[6];
    const float* b_ih   = (const float*)d_in[7];
    const float* whh_f  = (const float*)d_in[8];
    const float* b_hh   = (const float*)d_in[9];
    const float* qw_f   = (const float*)d_in[10];
    const float* q_b    = (const float*)d_in[11];
    const float* kw_f   = (const float*)d_in[12];
    // d_in[13] = k_b: softmax-invariant, dropped.
    const float* vw_f   = (const float*)d_in[14];
    const float* v_b    = (const float*)d_in[15];
    const float* f2aw_f = (const float*)d_in[16];
    const float* f2a_b  = (const float*)d_in[17];
    const float* f2bw_f = (const float*)d_in[18];
    const float* f2b_b  = (const float*)d_in[19];

    bf16* ws = (bf16*)d_ws;
    bf16* Wfc1 = ws + OFF_WFC1;
    bf16* WrX  = ws + OFF_WRX;
    bf16* WzX  = ws + OFF_WZX;
    bf16* Wni  = ws + OFF_WNI;
    bf16* WrH  = ws + OFF_WRH;
    bf16* WzH  = ws + OFF_WZH;
    bf16* Wnh  = ws + OFF_WNH;
    bf16* Wq   = ws + OFF_WQ;
    bf16* Wkv  = ws + OFF_WKV;
    bf16* f2aH = ws + OFF_F2AH;
    bf16* f2aM = ws + OFF_F2AM;
    bf16* Wf2b = ws + OFF_WF2B;
    bf16* insw = ws + OFF_INSW;

    float* q_out    = (float*)d_out;                 // [16384,16]
    float* h_out    = q_out + (size_t)ROWS * 16;     // [16384,256]
    float* magg_out = h_out + (size_t)ROWS * 256;    // [16384,256]

    // 1) swizzle weights + 'in' activations to fragment-major bf16
    SwzArgs sa{};
    int s = 0;
    auto add = [&](const float* src, bf16* dst, int N, int K, int ld) {
        sa.seg[s].src = src; sa.seg[s].dst = dst;
        sa.seg[s].items = N * (K >> 3);
        sa.seg[s].k8s = (K == 128) ? 4 : 5;
        sa.seg[s].k32 = K >> 5;
        sa.seg[s].ld = ld; ++s;
    };
    add(fc1w_f,          Wfc1, 256, 128, 128);
    add(wih_f,           WrX,  256, 256, 256);
    add(wih_f +  65536,  WzX,  256, 256, 256);
    add(wih_f + 131072,  Wni,  256, 256, 256);
    add(whh_f,           WrH,  256, 256, 256);
    add(whh_f +  65536,  WzH,  256, 256, 256);
    add(whh_f + 131072,  Wnh,  256, 256, 256);
    add(qw_f,            Wq,    64, 256, 256);
    add(kw_f,            Wkv,   64, 256, 256);
    add(vw_f,            Wkv + 16384, 256, 256, 256);
    add(f2aw_f,          f2aH, 256, 256, 512);
    add(f2aw_f + 256,    f2aM, 256, 256, 512);
    add(f2bw_f,          Wf2b,  16, 256, 256);
    add(in_f,            insw, 16384, 128, 128);
    sa.count = s;
    swz_k<<<512, 256, 0, stream>>>(sa);

    // 2) fully fused per-batch megakernel (256 blocks = 1/CU)
    mega_k<<<256, 512, 0, stream>>>(insw, hid_f, msg_f, topk,
                                    Wfc1, fc1_b, WrX, WrH, WzX, WzH, Wni, Wnh,
                                    b_ih, b_hh, Wq, q_b, Wkv, v_b,
                                    f2aH, f2aM, f2a_b, Wf2b, f2b_b,
                                    h_out, magg_out, q_out);
}